// Round 5
// baseline (204.079 us; speedup 1.0000x reference)
//
#include <hip/hip_runtime.h>

// Output layout (flat f32, reference return order):
//   out0 : (1024,50,3)  @ 0       (153600)
//   steps: (1024,3,49)  @ 153600  (150528)  all 0.01
//   eps  : (1024,3)     @ 304128  (3072)    analytic 0
//   var  : (1024,50,3)  @ 307200  (153600)
//   xi   : (1,10,3)     @ 460800  (30)
#define OUT0_OFF  0
#define STEPS_OFF 153600
#define EPS_OFF   304128
#define VAR_OFF   307200
#define XI_OFF    460800

__device__ __forceinline__ void fma64(const float4& a0, const float4& a1,
                                      const float4& b0, const float4& b1,
                                      float acc[8][8]) {
    const float a_[8] = {a0.x, a0.y, a0.z, a0.w, a1.x, a1.y, a1.z, a1.w};
    const float b_[8] = {b0.x, b0.y, b0.z, b0.w, b1.x, b1.y, b1.z, b1.w};
    #pragma unroll
    for (int i = 0; i < 8; ++i)
        #pragma unroll
        for (int j = 0; j < 8; ++j)
            acc[i][j] = fmaf(a_[i], b_[j], acc[i][j]);
}

// ---------------- GEMM1 + mv1 piggyback ---------------------------------------
// Main: H1 = relu(net_iv(1024x150) @ nW1(150x1024) + nb1). 32x64 tile, 128 thr.
// Blocks with bx==16: mv1  h1p = relu(param_in(64) @ pW1 + pb1)  (32 blocks).
__global__ __launch_bounds__(128)
void gemm1_k150(const float* __restrict__ A, const float* __restrict__ B,
                const float* __restrict__ bias, float* __restrict__ C,
                const float* __restrict__ px, const float* __restrict__ pW1,
                const float* __restrict__ pb1, float* __restrict__ h1p)
{
    __shared__ __align__(16) float As[150][36];   // transposed A, 21.6 KB
    __shared__ __align__(16) float Bs[150][64];   // 38.4 KB
    const int t = threadIdx.x;

    if (blockIdx.x == 16) {                       // mv1: 32 blocks x 32 j
        float* red = &As[0][0];
        const int jj = t & 31, kg = t >> 5;       // 4 kgroups x 16 k
        const int j = blockIdx.y * 32 + jj;
        float acc = 0.f;
        for (int k = kg * 16; k < kg * 16 + 16; ++k)
            acc = fmaf(px[k], pW1[k * 1024 + j], acc);
        red[kg * 32 + jj] = acc;
        __syncthreads();
        if (kg == 0) {
            float s = red[jj] + red[32 + jj] + red[64 + jj] + red[96 + jj];
            h1p[j] = fmaxf(s + pb1[j], 0.f);
        }
        return;
    }

    const int col0 = blockIdx.x * 64;
    const int row0 = blockIdx.y * 32;

    for (int i = t; i < 4800; i += 128) {
        const int r = i / 150;
        const int k = i - r * 150;
        As[k][r] = A[row0 * 150 + i];
    }
    {
        const int c4 = (t & 15) * 4;
        for (int k = t >> 4; k < 150; k += 8)
            *(float4*)&Bs[k][c4] = *(const float4*)(B + k * 1024 + col0 + c4);
    }
    __syncthreads();

    const int tx4 = (t & 15) * 4;
    const int ty4 = (t >> 4) * 4;
    float acc[4][4] = {};
    #pragma unroll 6
    for (int k = 0; k < 150; ++k) {
        float4 av = *(const float4*)&As[k][ty4];
        float4 bv = *(const float4*)&Bs[k][tx4];
        const float a_[4] = {av.x, av.y, av.z, av.w};
        const float b_[4] = {bv.x, bv.y, bv.z, bv.w};
        #pragma unroll
        for (int i = 0; i < 4; ++i)
            #pragma unroll
            for (int j = 0; j < 4; ++j)
                acc[i][j] = fmaf(a_[i], b_[j], acc[i][j]);
    }
    #pragma unroll
    for (int i = 0; i < 4; ++i) {
        const int r = row0 + ty4 + i;
        #pragma unroll
        for (int j = 0; j < 4; ++j) {
            const int c = col0 + tx4 + j;
            C[r * 1024 + c] = fmaxf(acc[i][j] + bias[c], 0.f);
        }
    }
}

// ---------------- gemm_tile8: 128x128 tile, 8x8 micro, BK=16 dbuf, split-K ----
// Simple inner loop (no explicit rotation) — compiler schedules ds_reads.
// Blocks with z==SK run the mv2 matvec (h1p @ pW2 -> pvec), 64 blocks x 16 j.
template<bool MV2>
__global__ __launch_bounds__(256, 2)
void gemm_tile8(const float* __restrict__ A, const float* __restrict__ B,
                float* __restrict__ C, int lda, int N, int kchunk, long pstride,
                int SK, const float* __restrict__ mx, const float* __restrict__ mW,
                float* __restrict__ my)
{
    __shared__ __align__(16) float As[2][16][132];
    __shared__ __align__(16) float Bs[2][16][132];
    const int t = threadIdx.x;

    if constexpr (MV2) {
        if (blockIdx.z == (unsigned)SK) {
            float* red = &As[0][0][0];
            const int jj = t & 15, kg = t >> 4;
            const int j = (blockIdx.y * gridDim.x + blockIdx.x) * 16 + jj;
            float acc = 0.f;
            const int k0 = kg * 64;
            for (int k = k0; k < k0 + 64; ++k)
                acc = fmaf(mx[k], mW[k * 1024 + j], acc);
            red[kg * 16 + jj] = acc;
            __syncthreads();
            if (kg == 0) {
                float s = 0.f;
                #pragma unroll
                for (int g = 0; g < 16; ++g) s += red[g * 16 + jj];
                my[j] = s;
            }
            return;
        }
    }

    const int col0 = blockIdx.x * 128;
    const int row0 = blockIdx.y * 128;
    const int k0   = blockIdx.z * kchunk;
    const int nk   = kchunk >> 4;

    float4 ga[2], gb[2];
    auto loadG = [&](int kt) {
        const int kbase = k0 + kt * 16;
        #pragma unroll
        for (int i = 0; i < 2; ++i) {
            const int idx = i * 256 + t;
            ga[i] = *(const float4*)(A + (long)(row0 + (idx >> 2)) * lda +
                                     kbase + (idx & 3) * 4);
            gb[i] = *(const float4*)(B + (long)(kbase + (idx >> 5)) * N +
                                     col0 + (idx & 31) * 4);
        }
    };
    auto writeL = [&](int buf) {
        #pragma unroll
        for (int i = 0; i < 2; ++i) {
            const int idx = i * 256 + t;
            const int r = idx >> 2, kq = (idx & 3) * 4;
            As[buf][kq + 0][r] = ga[i].x;
            As[buf][kq + 1][r] = ga[i].y;
            As[buf][kq + 2][r] = ga[i].z;
            As[buf][kq + 3][r] = ga[i].w;
            *(float4*)&Bs[buf][idx >> 5][(idx & 31) * 4] = gb[i];
        }
    };

    loadG(0);
    writeL(0);
    __syncthreads();

    const int tx4 = (t & 15) * 4;
    const int ty4 = (t >> 4) * 4;
    float acc[8][8] = {};

    for (int kt = 0; kt < nk; ++kt) {
        const int cur = kt & 1;
        if (kt + 1 < nk) loadG(kt + 1);          // T14: issue early
        #pragma unroll
        for (int kk = 0; kk < 16; ++kk) {
            float4 a0 = *(const float4*)&As[cur][kk][ty4];
            float4 a1 = *(const float4*)&As[cur][kk][64 + ty4];
            float4 b0 = *(const float4*)&Bs[cur][kk][tx4];
            float4 b1 = *(const float4*)&Bs[cur][kk][64 + tx4];
            fma64(a0, a1, b0, b1, acc);
        }
        if (kt + 1 < nk) writeL(cur ^ 1);        // write late
        __syncthreads();
    }

    float* Cb = C + (long)blockIdx.z * pstride;
    #pragma unroll
    for (int h = 0; h < 2; ++h) {
        #pragma unroll
        for (int i = 0; i < 4; ++i) {
            const long r = row0 + h * 64 + ty4 + i;
            float4 v0 = {acc[h*4+i][0], acc[h*4+i][1], acc[h*4+i][2], acc[h*4+i][3]};
            float4 v1 = {acc[h*4+i][4], acc[h*4+i][5], acc[h*4+i][6], acc[h*4+i][7]};
            *(float4*)&Cb[r * N + col0 + tx4]      = v0;
            *(float4*)&Cb[r * N + col0 + 64 + tx4] = v1;
        }
    }
}

// ---------------- gemm84: 64x64 tile, 8x4 micro, 128 thr, BK=16 dbuf ----------
__global__ __launch_bounds__(128, 2)
void gemm84(const float* __restrict__ A, const float* __restrict__ B,
            float* __restrict__ C, int lda, int N, int kchunk, long pstride)
{
    __shared__ __align__(16) float As[2][16][68];
    __shared__ __align__(16) float Bs[2][16][68];
    const int t = threadIdx.x;
    const int col0 = blockIdx.x * 64;
    const int row0 = blockIdx.y * 64;
    const int k0   = blockIdx.z * kchunk;
    const int nk   = kchunk >> 4;

    float4 ga[2], gb[2];
    auto loadG = [&](int kt) {
        const int kbase = k0 + kt * 16;
        #pragma unroll
        for (int i = 0; i < 2; ++i) {
            const int idx = i * 128 + t;
            ga[i] = *(const float4*)(A + (long)(row0 + (idx >> 2)) * lda +
                                     kbase + (idx & 3) * 4);
            gb[i] = *(const float4*)(B + (long)(kbase + (idx >> 4)) * N +
                                     col0 + (idx & 15) * 4);
        }
    };
    auto writeL = [&](int buf) {
        #pragma unroll
        for (int i = 0; i < 2; ++i) {
            const int idx = i * 128 + t;
            const int r = idx >> 2, kq = (idx & 3) * 4;
            As[buf][kq + 0][r] = ga[i].x;
            As[buf][kq + 1][r] = ga[i].y;
            As[buf][kq + 2][r] = ga[i].z;
            As[buf][kq + 3][r] = ga[i].w;
            *(float4*)&Bs[buf][idx >> 4][(idx & 15) * 4] = gb[i];
        }
    };

    loadG(0);
    writeL(0);
    __syncthreads();

    const int tx4 = (t & 15) * 4;
    const int ty8 = (t >> 4) * 8;
    float acc[8][4] = {};

    for (int kt = 0; kt < nk; ++kt) {
        const int cur = kt & 1;
        if (kt + 1 < nk) loadG(kt + 1);
        #pragma unroll
        for (int kk = 0; kk < 16; ++kk) {
            float4 a0 = *(const float4*)&As[cur][kk][ty8];
            float4 a1 = *(const float4*)&As[cur][kk][ty8 + 4];
            float4 bv = *(const float4*)&Bs[cur][kk][tx4];
            const float a_[8] = {a0.x, a0.y, a0.z, a0.w, a1.x, a1.y, a1.z, a1.w};
            const float b_[4] = {bv.x, bv.y, bv.z, bv.w};
            #pragma unroll
            for (int i = 0; i < 8; ++i)
                #pragma unroll
                for (int j = 0; j < 4; ++j)
                    acc[i][j] = fmaf(a_[i], b_[j], acc[i][j]);
        }
        if (kt + 1 < nk) writeL(cur ^ 1);
        __syncthreads();
    }

    float* Cb = C + (long)blockIdx.z * pstride;
    #pragma unroll
    for (int i = 0; i < 8; ++i) {
        const long r = row0 + ty8 + i;
        float4 v = {acc[i][0], acc[i][1], acc[i][2], acc[i][3]};
        *(float4*)&Cb[r * N + col0 + tx4] = v;
    }
}

// ---------------- reduce GEMM2 split-K=8 (+bias+relu) + mv3 piggyback ---------
__global__ __launch_bounds__(256)
void reduce8_mv3(const float* __restrict__ P, const float* __restrict__ bias,
                 float* __restrict__ H2,
                 const float* __restrict__ pvec, const float* __restrict__ pb2,
                 const float* __restrict__ pW3, const float* __restrict__ pb3,
                 const float* __restrict__ mask, float* __restrict__ xi)
{
    const int t = threadIdx.x;
    if (blockIdx.x >= 1024) {                 // mv3: 15 blocks x 2 j
        const int bid = blockIdx.x - 1024;
        const int j = bid * 2 + (t >> 7);
        const int lane = t & 127;
        float acc = 0.f;
        for (int k = lane; k < 1024; k += 128) {
            float h = fmaxf(pvec[k] + pb2[k], 0.f);
            acc = fmaf(h, pW3[k * 30 + j], acc);
        }
        #pragma unroll
        for (int off = 32; off > 0; off >>= 1) acc += __shfl_down(acc, off, 64);
        __shared__ float red[4];
        if ((t & 63) == 0) red[t >> 6] = acc;
        __syncthreads();
        if ((t & 127) == 0)
            xi[j] = (red[t >> 6] + red[(t >> 6) + 1] + pb3[j]) * mask[j];
        return;
    }
    const int i4 = blockIdx.x * 256 + t;
    float4 s = ((const float4*)P)[i4];
    #pragma unroll
    for (int p = 1; p < 8; ++p) {
        float4 q = ((const float4*)(P + (long)p * 1048576))[i4];
        s.x += q.x; s.y += q.y; s.z += q.z; s.w += q.w;
    }
    const int c0 = (i4 << 2) & 1023;
    float4 bv = *(const float4*)&bias[c0];
    float4 v;
    v.x = fmaxf(s.x + bv.x, 0.f);
    v.y = fmaxf(s.y + bv.y, 0.f);
    v.z = fmaxf(s.z + bv.z, 0.f);
    v.w = fmaxf(s.w + bv.w, 0.f);
    ((float4*)H2)[i4] = v;
}

// ---------------- pad nW3 (1024x150) -> B3p (1024x192, zero-padded) -----------
__global__ __launch_bounds__(256)
void pad_w3(const float* __restrict__ w, float* __restrict__ o)
{
    const int i = blockIdx.x * 256 + threadIdx.x;   // 196608
    const int k = i / 192, c = i - k * 192;
    o[i] = (c < 150) ? w[k * 150 + c] : 0.f;
}

// ---------------- ode: GEMM3 16-way reduce + basis/rhs/trapezoid, 4 b/block ---
__global__ __launch_bounds__(256)
void ode_kernel(const float* __restrict__ P3, const float* __restrict__ nb3,
                const float* __restrict__ xi, float* __restrict__ varp,
                float* __restrict__ out0, float* __restrict__ steps,
                float* __restrict__ eps)
{
    const int t  = threadIdx.x;
    const int bl = t >> 6;                    // 0..3
    const int b  = blockIdx.x * 4 + bl;
    const int lt = t & 63;
    __shared__ float s_var[4][152];
    __shared__ float s_xi[30];
    __shared__ float s_rhs[4][50][3];
    if (t < 30) s_xi[t] = xi[t];
    for (int i = lt; i < 150; i += 64) {
        float v = nb3[i];
        #pragma unroll
        for (int s = 0; s < 16; ++s) v += P3[s * 196608 + b * 192 + i];
        s_var[bl][i] = v;
        varp[b * 150 + i] = v;
    }
    __syncthreads();
    if (lt < 50) {
        const float v0 = s_var[bl][lt * 3 + 0];
        const float v1 = s_var[bl][lt * 3 + 1];
        const float v2 = s_var[bl][lt * 3 + 2];
        const float bas[10] = {1.f, v0, v1, v2,
                               v0 * v0, v0 * v1, v0 * v2,
                               v1 * v1, v1 * v2, v2 * v2};
        #pragma unroll
        for (int d = 0; d < 3; ++d) {
            float r = 0.f;
            #pragma unroll
            for (int k = 0; k < 10; ++k) r = fmaf(bas[k], s_xi[k * 3 + d], r);
            s_rhs[bl][lt][d] = r;
        }
    }
    __syncthreads();
    if (lt < 3) {
        float x = s_var[bl][lt];              // iv = var[b,0,lt]
        out0[b * 150 + lt] = x;
        for (int n = 1; n < 50; ++n) {
            x = fmaf(0.005f, s_rhs[bl][n - 1][lt] + s_rhs[bl][n][lt], x);
            out0[b * 150 + n * 3 + lt] = x;
        }
        eps[b * 3 + lt] = 0.f;
    }
    for (int i = lt; i < 147; i += 64) steps[b * 147 + i] = 0.01f;
}

extern "C" void kernel_launch(void* const* d_in, const int* in_sizes, int n_in,
                              void* d_out, int out_size, void* d_ws, size_t ws_size,
                              hipStream_t stream)
{
    const float* net_iv   = (const float*)d_in[0];
    const float* param_in = (const float*)d_in[1];
    const float* pW1 = (const float*)d_in[2];
    const float* pb1 = (const float*)d_in[3];
    const float* pW2 = (const float*)d_in[4];
    const float* pb2 = (const float*)d_in[5];
    const float* pW3 = (const float*)d_in[6];
    const float* pb3 = (const float*)d_in[7];
    const float* nW1 = (const float*)d_in[8];
    const float* nb1 = (const float*)d_in[9];
    const float* nW2 = (const float*)d_in[10];
    const float* nb2 = (const float*)d_in[11];
    const float* nW3 = (const float*)d_in[12];
    const float* nb3 = (const float*)d_in[13];
    const float* mask= (const float*)d_in[14];

    float* out = (float*)d_out;
    float* out0p  = out + OUT0_OFF;
    float* stepsp = out + STEPS_OFF;
    float* epsp   = out + EPS_OFF;
    float* varp   = out + VAR_OFF;
    float* xip    = out + XI_OFF;

    // ws layout (floats); ws = 256 MiB, we use ~54 MB.
    float* H1   = (float*)d_ws;              // 1048576
    float* P2   = H1 + 1048576;              // 8 x 1048576 (GEMM2 partials)
    float* H2   = P2 + 8388608;              // 1048576
    float* P3   = H2 + 1048576;              // 16 x 196608 (GEMM3 partials)
    float* B3p  = P3 + 3145728;              // 196608 (padded nW3)
    float* pvec = B3p + 196608;              // 1024
    float* h1p  = pvec + 1024;               // 1024

    // pad nW3 -> B3p (independent, run first)
    hipLaunchKernelGGL(pad_w3, dim3(768), dim3(256), 0, stream, nW3, B3p);

    // k1: GEMM1 (+ mv1 piggyback on bx==16)
    hipLaunchKernelGGL(gemm1_k150, dim3(17, 32), dim3(128), 0, stream,
                       net_iv, nW1, nb1, H1, param_in, pW1, pb1, h1p);

    // k2: GEMM2 128x128, 8x8 micro, split-K=8 (+ mv2 piggyback on z==8)
    hipLaunchKernelGGL((gemm_tile8<true>), dim3(8, 8, 9), dim3(256), 0, stream,
                       H1, nW2, P2, 1024, 1024, 128, 1048576L, 8,
                       h1p, pW2, pvec);

    // k3: reduce 8 partials + bias + relu -> H2 (+ mv3 piggyback)
    hipLaunchKernelGGL(reduce8_mv3, dim3(1039), dim3(256), 0, stream,
                       P2, nb2, H2, pvec, pb2, pW3, pb3, mask, xip);

    // k4: GEMM3 64x64, 8x4 micro, split-K=16, padded B (N=192)
    hipLaunchKernelGGL(gemm84, dim3(3, 16, 16), dim3(128), 0, stream,
                       H2, B3p, P3, 1024, 192, 64, 196608L);

    // k5: ode (reduce 16 partials + basis/rhs/trapezoid + fills)
    hipLaunchKernelGGL(ode_kernel, dim3(256), dim3(256), 0, stream,
                       P3, nb3, xip, varp, out0p, stepsp, epsp);
}

// Round 6
// 123.489 us; speedup vs baseline: 1.6526x; 1.6526x over previous
//
#include <hip/hip_runtime.h>

// Output layout (flat f32, reference return order):
//   out0 : (1024,50,3)  @ 0       (153600)
//   steps: (1024,3,49)  @ 153600  (150528)  all 0.01
//   eps  : (1024,3)     @ 304128  (3072)    analytic 0
//   var  : (1024,50,3)  @ 307200  (153600)
//   xi   : (1,10,3)     @ 460800  (30)
#define OUT0_OFF  0
#define STEPS_OFF 153600
#define EPS_OFF   304128
#define VAR_OFF   307200
#define XI_OFF    460800

__device__ __forceinline__ void fma64(const float4& a0, const float4& a1,
                                      const float4& b0, const float4& b1,
                                      float acc[8][8]) {
    const float a_[8] = {a0.x, a0.y, a0.z, a0.w, a1.x, a1.y, a1.z, a1.w};
    const float b_[8] = {b0.x, b0.y, b0.z, b0.w, b1.x, b1.y, b1.z, b1.w};
    #pragma unroll
    for (int i = 0; i < 8; ++i)
        #pragma unroll
        for (int j = 0; j < 8; ++j)
            acc[i][j] = fmaf(a_[i], b_[j], acc[i][j]);
}

// ---------------- GEMM1 + mv1 piggyback ---------------------------------------
// Main: H1 = relu(net_iv(1024x150) @ nW1(150x1024) + nb1). 32x64 tile, 128 thr.
// Blocks with bx==16: mv1  h1p = relu(param_in(64) @ pW1 + pb1)  (32 blocks).
__global__ __launch_bounds__(128)
void gemm1_k150(const float* __restrict__ A, const float* __restrict__ B,
                const float* __restrict__ bias, float* __restrict__ C,
                const float* __restrict__ px, const float* __restrict__ pW1,
                const float* __restrict__ pb1, float* __restrict__ h1p)
{
    __shared__ __align__(16) float As[150][36];   // transposed A, 21.6 KB
    __shared__ __align__(16) float Bs[150][64];   // 38.4 KB
    const int t = threadIdx.x;

    if (blockIdx.x == 16) {                       // mv1: 32 blocks x 32 j
        float* red = &As[0][0];
        const int jj = t & 31, kg = t >> 5;       // 4 kgroups x 16 k
        const int j = blockIdx.y * 32 + jj;
        float acc = 0.f;
        for (int k = kg * 16; k < kg * 16 + 16; ++k)
            acc = fmaf(px[k], pW1[k * 1024 + j], acc);
        red[kg * 32 + jj] = acc;
        __syncthreads();
        if (kg == 0) {
            float s = red[jj] + red[32 + jj] + red[64 + jj] + red[96 + jj];
            h1p[j] = fmaxf(s + pb1[j], 0.f);
        }
        return;
    }

    const int col0 = blockIdx.x * 64;
    const int row0 = blockIdx.y * 32;

    for (int i = t; i < 4800; i += 128) {
        const int r = i / 150;
        const int k = i - r * 150;
        As[k][r] = A[row0 * 150 + i];
    }
    {
        const int c4 = (t & 15) * 4;
        for (int k = t >> 4; k < 150; k += 8)
            *(float4*)&Bs[k][c4] = *(const float4*)(B + k * 1024 + col0 + c4);
    }
    __syncthreads();

    const int tx4 = (t & 15) * 4;
    const int ty4 = (t >> 4) * 4;
    float acc[4][4] = {};
    #pragma unroll 6
    for (int k = 0; k < 150; ++k) {
        float4 av = *(const float4*)&As[k][ty4];
        float4 bv = *(const float4*)&Bs[k][tx4];
        const float a_[4] = {av.x, av.y, av.z, av.w};
        const float b_[4] = {bv.x, bv.y, bv.z, bv.w};
        #pragma unroll
        for (int i = 0; i < 4; ++i)
            #pragma unroll
            for (int j = 0; j < 4; ++j)
                acc[i][j] = fmaf(a_[i], b_[j], acc[i][j]);
    }
    #pragma unroll
    for (int i = 0; i < 4; ++i) {
        const int r = row0 + ty4 + i;
        #pragma unroll
        for (int j = 0; j < 4; ++j) {
            const int c = col0 + tx4 + j;
            C[r * 1024 + c] = fmaxf(acc[i][j] + bias[c], 0.f);
        }
    }
}

// ---------------- gemm_tile8: 128x128 tile, 8x8 micro, BK=16 dbuf, split-K ----
// NOTE: __launch_bounds__(256,1) — do NOT raise min-waves: (256,2) caps VGPR
// at 128 and spills the 64-reg accumulator to scratch (R5: 441 MB writes).
// Blocks with z==SK run the mv2 matvec (h1p @ pW2 -> pvec), 64 blocks x 16 j.
template<bool MV2>
__global__ __launch_bounds__(256, 1)
void gemm_tile8(const float* __restrict__ A, const float* __restrict__ B,
                float* __restrict__ C, int lda, int N, int kchunk, long pstride,
                int SK, const float* __restrict__ mx, const float* __restrict__ mW,
                float* __restrict__ my)
{
    __shared__ __align__(16) float As[2][16][132];
    __shared__ __align__(16) float Bs[2][16][132];
    const int t = threadIdx.x;

    if constexpr (MV2) {
        if (blockIdx.z == (unsigned)SK) {
            float* red = &As[0][0][0];
            const int jj = t & 15, kg = t >> 4;
            const int j = (blockIdx.y * gridDim.x + blockIdx.x) * 16 + jj;
            float acc = 0.f;
            const int k0 = kg * 64;
            for (int k = k0; k < k0 + 64; ++k)
                acc = fmaf(mx[k], mW[k * 1024 + j], acc);
            red[kg * 16 + jj] = acc;
            __syncthreads();
            if (kg == 0) {
                float s = 0.f;
                #pragma unroll
                for (int g = 0; g < 16; ++g) s += red[g * 16 + jj];
                my[j] = s;
            }
            return;
        }
    }

    const int col0 = blockIdx.x * 128;
    const int row0 = blockIdx.y * 128;
    const int k0   = blockIdx.z * kchunk;
    const int nk   = kchunk >> 4;

    float4 ga[2], gb[2];
    auto loadG = [&](int kt) {
        const int kbase = k0 + kt * 16;
        #pragma unroll
        for (int i = 0; i < 2; ++i) {
            const int idx = i * 256 + t;
            ga[i] = *(const float4*)(A + (long)(row0 + (idx >> 2)) * lda +
                                     kbase + (idx & 3) * 4);
            gb[i] = *(const float4*)(B + (long)(kbase + (idx >> 5)) * N +
                                     col0 + (idx & 31) * 4);
        }
    };
    auto writeL = [&](int buf) {
        #pragma unroll
        for (int i = 0; i < 2; ++i) {
            const int idx = i * 256 + t;
            const int r = idx >> 2, kq = (idx & 3) * 4;
            As[buf][kq + 0][r] = ga[i].x;
            As[buf][kq + 1][r] = ga[i].y;
            As[buf][kq + 2][r] = ga[i].z;
            As[buf][kq + 3][r] = ga[i].w;
            *(float4*)&Bs[buf][idx >> 5][(idx & 31) * 4] = gb[i];
        }
    };

    loadG(0);
    writeL(0);
    __syncthreads();

    const int tx4 = (t & 15) * 4;
    const int ty4 = (t >> 4) * 4;
    float acc[8][8] = {};

    for (int kt = 0; kt < nk; ++kt) {
        const int cur = kt & 1;
        if (kt + 1 < nk) loadG(kt + 1);          // T14: issue early
        #pragma unroll
        for (int kk = 0; kk < 16; ++kk) {
            float4 a0 = *(const float4*)&As[cur][kk][ty4];
            float4 a1 = *(const float4*)&As[cur][kk][64 + ty4];
            float4 b0 = *(const float4*)&Bs[cur][kk][tx4];
            float4 b1 = *(const float4*)&Bs[cur][kk][64 + tx4];
            fma64(a0, a1, b0, b1, acc);
        }
        if (kt + 1 < nk) writeL(cur ^ 1);        // write late
        __syncthreads();
    }

    float* Cb = C + (long)blockIdx.z * pstride;
    #pragma unroll
    for (int h = 0; h < 2; ++h) {
        #pragma unroll
        for (int i = 0; i < 4; ++i) {
            const long r = row0 + h * 64 + ty4 + i;
            float4 v0 = {acc[h*4+i][0], acc[h*4+i][1], acc[h*4+i][2], acc[h*4+i][3]};
            float4 v1 = {acc[h*4+i][4], acc[h*4+i][5], acc[h*4+i][6], acc[h*4+i][7]};
            *(float4*)&Cb[r * N + col0 + tx4]      = v0;
            *(float4*)&Cb[r * N + col0 + 64 + tx4] = v1;
        }
    }
}

// ---------------- gemm84: 64x64 tile, 8x4 micro, 128 thr, BK=16 dbuf ----------
__global__ __launch_bounds__(128, 1)
void gemm84(const float* __restrict__ A, const float* __restrict__ B,
            float* __restrict__ C, int lda, int N, int kchunk, long pstride)
{
    __shared__ __align__(16) float As[2][16][68];
    __shared__ __align__(16) float Bs[2][16][68];
    const int t = threadIdx.x;
    const int col0 = blockIdx.x * 64;
    const int row0 = blockIdx.y * 64;
    const int k0   = blockIdx.z * kchunk;
    const int nk   = kchunk >> 4;

    float4 ga[2], gb[2];
    auto loadG = [&](int kt) {
        const int kbase = k0 + kt * 16;
        #pragma unroll
        for (int i = 0; i < 2; ++i) {
            const int idx = i * 128 + t;
            ga[i] = *(const float4*)(A + (long)(row0 + (idx >> 2)) * lda +
                                     kbase + (idx & 3) * 4);
            gb[i] = *(const float4*)(B + (long)(kbase + (idx >> 4)) * N +
                                     col0 + (idx & 15) * 4);
        }
    };
    auto writeL = [&](int buf) {
        #pragma unroll
        for (int i = 0; i < 2; ++i) {
            const int idx = i * 128 + t;
            const int r = idx >> 2, kq = (idx & 3) * 4;
            As[buf][kq + 0][r] = ga[i].x;
            As[buf][kq + 1][r] = ga[i].y;
            As[buf][kq + 2][r] = ga[i].z;
            As[buf][kq + 3][r] = ga[i].w;
            *(float4*)&Bs[buf][idx >> 4][(idx & 15) * 4] = gb[i];
        }
    };

    loadG(0);
    writeL(0);
    __syncthreads();

    const int tx4 = (t & 15) * 4;
    const int ty8 = (t >> 4) * 8;
    float acc[8][4] = {};

    for (int kt = 0; kt < nk; ++kt) {
        const int cur = kt & 1;
        if (kt + 1 < nk) loadG(kt + 1);
        #pragma unroll
        for (int kk = 0; kk < 16; ++kk) {
            float4 a0 = *(const float4*)&As[cur][kk][ty8];
            float4 a1 = *(const float4*)&As[cur][kk][ty8 + 4];
            float4 bv = *(const float4*)&Bs[cur][kk][tx4];
            const float a_[8] = {a0.x, a0.y, a0.z, a0.w, a1.x, a1.y, a1.z, a1.w};
            const float b_[4] = {bv.x, bv.y, bv.z, bv.w};
            #pragma unroll
            for (int i = 0; i < 8; ++i)
                #pragma unroll
                for (int j = 0; j < 4; ++j)
                    acc[i][j] = fmaf(a_[i], b_[j], acc[i][j]);
        }
        if (kt + 1 < nk) writeL(cur ^ 1);
        __syncthreads();
    }

    float* Cb = C + (long)blockIdx.z * pstride;
    #pragma unroll
    for (int i = 0; i < 8; ++i) {
        const long r = row0 + ty8 + i;
        float4 v = {acc[i][0], acc[i][1], acc[i][2], acc[i][3]};
        *(float4*)&Cb[r * N + col0 + tx4] = v;
    }
}

// ---------------- reduce GEMM2 split-K=8 (+bias+relu) + mv3 piggyback ---------
__global__ __launch_bounds__(256)
void reduce8_mv3(const float* __restrict__ P, const float* __restrict__ bias,
                 float* __restrict__ H2,
                 const float* __restrict__ pvec, const float* __restrict__ pb2,
                 const float* __restrict__ pW3, const float* __restrict__ pb3,
                 const float* __restrict__ mask, float* __restrict__ xi)
{
    const int t = threadIdx.x;
    if (blockIdx.x >= 1024) {                 // mv3: 15 blocks x 2 j
        const int bid = blockIdx.x - 1024;
        const int j = bid * 2 + (t >> 7);
        const int lane = t & 127;
        float acc = 0.f;
        for (int k = lane; k < 1024; k += 128) {
            float h = fmaxf(pvec[k] + pb2[k], 0.f);
            acc = fmaf(h, pW3[k * 30 + j], acc);
        }
        #pragma unroll
        for (int off = 32; off > 0; off >>= 1) acc += __shfl_down(acc, off, 64);
        __shared__ float red[4];
        if ((t & 63) == 0) red[t >> 6] = acc;
        __syncthreads();
        if ((t & 127) == 0)
            xi[j] = (red[t >> 6] + red[(t >> 6) + 1] + pb3[j]) * mask[j];
        return;
    }
    const int i4 = blockIdx.x * 256 + t;
    float4 s = ((const float4*)P)[i4];
    #pragma unroll
    for (int p = 1; p < 8; ++p) {
        float4 q = ((const float4*)(P + (long)p * 1048576))[i4];
        s.x += q.x; s.y += q.y; s.z += q.z; s.w += q.w;
    }
    const int c0 = (i4 << 2) & 1023;
    float4 bv = *(const float4*)&bias[c0];
    float4 v;
    v.x = fmaxf(s.x + bv.x, 0.f);
    v.y = fmaxf(s.y + bv.y, 0.f);
    v.z = fmaxf(s.z + bv.z, 0.f);
    v.w = fmaxf(s.w + bv.w, 0.f);
    ((float4*)H2)[i4] = v;
}

// ---------------- pad nW3 (1024x150) -> B3p (1024x192, zero-padded) -----------
__global__ __launch_bounds__(256)
void pad_w3(const float* __restrict__ w, float* __restrict__ o)
{
    const int i = blockIdx.x * 256 + threadIdx.x;   // 196608
    const int k = i / 192, c = i - k * 192;
    o[i] = (c < 150) ? w[k * 150 + c] : 0.f;
}

// ---------------- ode: GEMM3 16-way reduce + basis/rhs/trapezoid, 4 b/block ---
__global__ __launch_bounds__(256)
void ode_kernel(const float* __restrict__ P3, const float* __restrict__ nb3,
                const float* __restrict__ xi, float* __restrict__ varp,
                float* __restrict__ out0, float* __restrict__ steps,
                float* __restrict__ eps)
{
    const int t  = threadIdx.x;
    const int bl = t >> 6;                    // 0..3
    const int b  = blockIdx.x * 4 + bl;
    const int lt = t & 63;
    __shared__ float s_var[4][152];
    __shared__ float s_xi[30];
    __shared__ float s_rhs[4][50][3];
    if (t < 30) s_xi[t] = xi[t];
    for (int i = lt; i < 150; i += 64) {
        float v = nb3[i];
        #pragma unroll
        for (int s = 0; s < 16; ++s) v += P3[s * 196608 + b * 192 + i];
        s_var[bl][i] = v;
        varp[b * 150 + i] = v;
    }
    __syncthreads();
    if (lt < 50) {
        const float v0 = s_var[bl][lt * 3 + 0];
        const float v1 = s_var[bl][lt * 3 + 1];
        const float v2 = s_var[bl][lt * 3 + 2];
        const float bas[10] = {1.f, v0, v1, v2,
                               v0 * v0, v0 * v1, v0 * v2,
                               v1 * v1, v1 * v2, v2 * v2};
        #pragma unroll
        for (int d = 0; d < 3; ++d) {
            float r = 0.f;
            #pragma unroll
            for (int k = 0; k < 10; ++k) r = fmaf(bas[k], s_xi[k * 3 + d], r);
            s_rhs[bl][lt][d] = r;
        }
    }
    __syncthreads();
    if (lt < 3) {
        float x = s_var[bl][lt];              // iv = var[b,0,lt]
        out0[b * 150 + lt] = x;
        for (int n = 1; n < 50; ++n) {
            x = fmaf(0.005f, s_rhs[bl][n - 1][lt] + s_rhs[bl][n][lt], x);
            out0[b * 150 + n * 3 + lt] = x;
        }
        eps[b * 3 + lt] = 0.f;
    }
    for (int i = lt; i < 147; i += 64) steps[b * 147 + i] = 0.01f;
}

extern "C" void kernel_launch(void* const* d_in, const int* in_sizes, int n_in,
                              void* d_out, int out_size, void* d_ws, size_t ws_size,
                              hipStream_t stream)
{
    const float* net_iv   = (const float*)d_in[0];
    const float* param_in = (const float*)d_in[1];
    const float* pW1 = (const float*)d_in[2];
    const float* pb1 = (const float*)d_in[3];
    const float* pW2 = (const float*)d_in[4];
    const float* pb2 = (const float*)d_in[5];
    const float* pW3 = (const float*)d_in[6];
    const float* pb3 = (const float*)d_in[7];
    const float* nW1 = (const float*)d_in[8];
    const float* nb1 = (const float*)d_in[9];
    const float* nW2 = (const float*)d_in[10];
    const float* nb2 = (const float*)d_in[11];
    const float* nW3 = (const float*)d_in[12];
    const float* nb3 = (const float*)d_in[13];
    const float* mask= (const float*)d_in[14];

    float* out = (float*)d_out;
    float* out0p  = out + OUT0_OFF;
    float* stepsp = out + STEPS_OFF;
    float* epsp   = out + EPS_OFF;
    float* varp   = out + VAR_OFF;
    float* xip    = out + XI_OFF;

    // ws layout (floats); ws = 256 MiB, we use ~54 MB.
    float* H1   = (float*)d_ws;              // 1048576
    float* P2   = H1 + 1048576;              // 8 x 1048576 (GEMM2 partials)
    float* H2   = P2 + 8388608;              // 1048576
    float* P3   = H2 + 1048576;              // 16 x 196608 (GEMM3 partials)
    float* B3p  = P3 + 3145728;              // 196608 (padded nW3)
    float* pvec = B3p + 196608;              // 1024
    float* h1p  = pvec + 1024;               // 1024

    // pad nW3 -> B3p (independent, run first)
    hipLaunchKernelGGL(pad_w3, dim3(768), dim3(256), 0, stream, nW3, B3p);

    // k1: GEMM1 (+ mv1 piggyback on bx==16)
    hipLaunchKernelGGL(gemm1_k150, dim3(17, 32), dim3(128), 0, stream,
                       net_iv, nW1, nb1, H1, param_in, pW1, pb1, h1p);

    // k2: GEMM2 128x128, 8x8 micro, split-K=8 (+ mv2 piggyback on z==8)
    hipLaunchKernelGGL((gemm_tile8<true>), dim3(8, 8, 9), dim3(256), 0, stream,
                       H1, nW2, P2, 1024, 1024, 128, 1048576L, 8,
                       h1p, pW2, pvec);

    // k3: reduce 8 partials + bias + relu -> H2 (+ mv3 piggyback)
    hipLaunchKernelGGL(reduce8_mv3, dim3(1039), dim3(256), 0, stream,
                       P2, nb2, H2, pvec, pb2, pW3, pb3, mask, xip);

    // k4: GEMM3 64x64, 8x4 micro, split-K=16, padded B (N=192)
    hipLaunchKernelGGL(gemm84, dim3(3, 16, 16), dim3(128), 0, stream,
                       H2, B3p, P3, 1024, 192, 64, 196608L);

    // k5: ode (reduce 16 partials + basis/rhs/trapezoid + fills)
    hipLaunchKernelGGL(ode_kernel, dim3(256), dim3(256), 0, stream,
                       P3, nb3, xip, varp, out0p, stepsp, epsp);
}

// Round 7
// 99.574 us; speedup vs baseline: 2.0495x; 1.2402x over previous
//
#include <hip/hip_runtime.h>

// Output layout (flat f32, reference return order):
//   out0 : (1024,50,3)  @ 0       (153600)
//   steps: (1024,3,49)  @ 153600  (150528)  all 0.01
//   eps  : (1024,3)     @ 304128  (3072)    analytic 0
//   var  : (1024,50,3)  @ 307200  (153600)
//   xi   : (1,10,3)     @ 460800  (30)
#define OUT0_OFF  0
#define STEPS_OFF 153600
#define EPS_OFF   304128
#define VAR_OFF   307200
#define XI_OFF    460800

__device__ __forceinline__ void fma16v(const float4& av, const float4& bv,
                                       float acc[4][4]) {
    const float a_[4] = {av.x, av.y, av.z, av.w};
    const float b_[4] = {bv.x, bv.y, bv.z, bv.w};
    #pragma unroll
    for (int i = 0; i < 4; ++i)
        #pragma unroll
        for (int j = 0; j < 4; ++j)
            acc[i][j] = fmaf(a_[i], b_[j], acc[i][j]);
}

// ---------------- GEMM1 + mv1 piggyback ---------------------------------------
// Main: H1 = relu(net_iv(1024x150) @ nW1(150x1024) + nb1). 32x64 tile, 128 thr,
// whole K in LDS (A transposed), 2-deep register rotation (R3-proven).
// Blocks with bx==16: mv1  h1p = relu(param_in(64) @ pW1 + pb1)  (32 blocks).
__global__ __launch_bounds__(128)
void gemm1_k150(const float* __restrict__ A, const float* __restrict__ B,
                const float* __restrict__ bias, float* __restrict__ C,
                const float* __restrict__ px, const float* __restrict__ pW1,
                const float* __restrict__ pb1, float* __restrict__ h1p)
{
    __shared__ __align__(16) float As[150][36];   // transposed A, 21.6 KB
    __shared__ __align__(16) float Bs[150][64];   // 38.4 KB
    const int t = threadIdx.x;

    if (blockIdx.x == 16) {                       // mv1: 32 blocks x 32 j
        float* red = &As[0][0];
        const int jj = t & 31, kg = t >> 5;       // 4 kgroups x 16 k
        const int j = blockIdx.y * 32 + jj;
        float acc = 0.f;
        for (int k = kg * 16; k < kg * 16 + 16; ++k)
            acc = fmaf(px[k], pW1[k * 1024 + j], acc);
        red[kg * 32 + jj] = acc;
        __syncthreads();
        if (kg == 0) {
            float s = red[jj] + red[32 + jj] + red[64 + jj] + red[96 + jj];
            h1p[j] = fmaxf(s + pb1[j], 0.f);
        }
        return;
    }

    const int col0 = blockIdx.x * 64;
    const int row0 = blockIdx.y * 32;

    for (int i = t; i < 4800; i += 128) {
        const int r = i / 150;
        const int k = i - r * 150;
        As[k][r] = A[row0 * 150 + i];
    }
    {
        const int c4 = (t & 15) * 4;
        for (int k = t >> 4; k < 150; k += 8)
            *(float4*)&Bs[k][c4] = *(const float4*)(B + k * 1024 + col0 + c4);
    }
    __syncthreads();

    const int tx4 = (t & 15) * 4;
    const int ty4 = (t >> 4) * 4;     // 0..28
    float acc[4][4] = {};
    float4 aA = *(const float4*)&As[0][ty4], bA = *(const float4*)&Bs[0][tx4];
    float4 aB = *(const float4*)&As[1][ty4], bB = *(const float4*)&Bs[1][tx4];
    #pragma unroll 5
    for (int k = 0; k < 150; k += 2) {
        float4 aN0 = {}, bN0 = {}, aN1 = {}, bN1 = {};
        if (k + 2 < 150) {
            aN0 = *(const float4*)&As[k + 2][ty4];
            bN0 = *(const float4*)&Bs[k + 2][tx4];
        }
        if (k + 3 < 150) {
            aN1 = *(const float4*)&As[k + 3][ty4];
            bN1 = *(const float4*)&Bs[k + 3][tx4];
        }
        fma16v(aA, bA, acc);
        fma16v(aB, bB, acc);
        aA = aN0; bA = bN0; aB = aN1; bB = bN1;
    }
    #pragma unroll
    for (int i = 0; i < 4; ++i) {
        const int r = row0 + ty4 + i;
        #pragma unroll
        for (int j = 0; j < 4; ++j) {
            const int c = col0 + tx4 + j;
            C[r * 1024 + c] = fmaxf(acc[i][j] + bias[c], 0.f);
        }
    }
}

// ---------------- gemm44: 64x64 tile, 4x4 micro, 256 thr, BK=16 dbuf ----------
// R3-proven config (84 VGPR -> 6 waves/SIMD; 16.9 KB LDS). 2-deep register
// rotation + T14 issue-early/write-late. Writes raw split-K partials.
// MV2: z==SK layer blocks with (by*gridDim.x+bx)<64 run mv2 matvec instead.
template<bool MV2>
__global__ __launch_bounds__(256, 1)
void gemm44(const float* __restrict__ A, const float* __restrict__ B,
            float* __restrict__ C, int lda, int N, int kchunk, long pstride,
            int SK, const float* __restrict__ mx, const float* __restrict__ mW,
            float* __restrict__ my)
{
    __shared__ __align__(16) float As[2][16][68];
    __shared__ __align__(16) float Bs[2][16][64];
    const int t = threadIdx.x;

    if constexpr (MV2) {
        if (blockIdx.z == (unsigned)SK) {
            const int idx = blockIdx.y * gridDim.x + blockIdx.x;
            if (idx >= 64) return;            // only 64 blocks needed
            float* red = &As[0][0][0];
            const int jj = t & 15, kg = t >> 4;
            const int j = idx * 16 + jj;
            float acc = 0.f;
            const int k0 = kg * 64;
            for (int k = k0; k < k0 + 64; ++k)
                acc = fmaf(mx[k], mW[k * 1024 + j], acc);
            red[kg * 16 + jj] = acc;
            __syncthreads();
            if (kg == 0) {
                float s = 0.f;
                #pragma unroll
                for (int g = 0; g < 16; ++g) s += red[g * 16 + jj];
                my[j] = s;
            }
            return;
        }
    }

    const int col0 = blockIdx.x * 64;
    const int row0 = blockIdx.y * 64;
    const int k0   = blockIdx.z * kchunk;
    const int nk   = kchunk >> 4;

    const int ar = t >> 2, ak = (t & 3) << 2;     // A stage: row, k-quad
    const int bk = t >> 4, bc = (t & 15) << 2;    // B stage: k, col-quad
    const float* Ap = A + (long)(row0 + ar) * lda + k0 + ak;
    const float* Bp0 = B + (long)(k0 + bk) * N + col0 + bc;

    float4 ga, gb;
    auto loadG = [&](int kt) {
        ga = *(const float4*)(Ap + kt * 16);
        gb = *(const float4*)(Bp0 + (long)kt * 16 * N);
    };
    auto writeL = [&](int buf) {
        As[buf][ak + 0][ar] = ga.x;
        As[buf][ak + 1][ar] = ga.y;
        As[buf][ak + 2][ar] = ga.z;
        As[buf][ak + 3][ar] = ga.w;
        *(float4*)&Bs[buf][bk][bc] = gb;
    };

    loadG(0);
    writeL(0);
    __syncthreads();

    const int tx4 = (t & 15) << 2;
    const int ty4 = (t >> 4) << 2;
    float acc[4][4] = {};
    for (int kt = 0; kt < nk; ++kt) {
        const int cur = kt & 1;
        if (kt + 1 < nk) loadG(kt + 1);          // T14: issue early

        float4 aA = *(const float4*)&As[cur][0][ty4];
        float4 bA = *(const float4*)&Bs[cur][0][tx4];
        float4 aB = *(const float4*)&As[cur][1][ty4];
        float4 bB = *(const float4*)&Bs[cur][1][tx4];
        #pragma unroll
        for (int kk = 0; kk < 16; kk += 2) {
            float4 aN0 = {}, bN0 = {}, aN1 = {}, bN1 = {};
            if (kk + 2 < 16) {
                aN0 = *(const float4*)&As[cur][kk + 2][ty4];
                bN0 = *(const float4*)&Bs[cur][kk + 2][tx4];
            }
            if (kk + 3 < 16) {
                aN1 = *(const float4*)&As[cur][kk + 3][ty4];
                bN1 = *(const float4*)&Bs[cur][kk + 3][tx4];
            }
            fma16v(aA, bA, acc);
            fma16v(aB, bB, acc);
            aA = aN0; bA = bN0; aB = aN1; bB = bN1;
        }

        if (kt + 1 < nk) writeL(cur ^ 1);        // write late
        __syncthreads();
    }

    float* Cb = C + (long)blockIdx.z * pstride;
    #pragma unroll
    for (int i = 0; i < 4; ++i) {
        const long r = row0 + ty4 + i;
        float4 v = {acc[i][0], acc[i][1], acc[i][2], acc[i][3]};
        *(float4*)&Cb[r * N + col0 + tx4] = v;
    }
}

// ---------------- reduce GEMM2 split-K=8 (+bias+relu) + mv3 piggyback ---------
__global__ __launch_bounds__(256)
void reduce8_mv3(const float* __restrict__ P, const float* __restrict__ bias,
                 float* __restrict__ H2,
                 const float* __restrict__ pvec, const float* __restrict__ pb2,
                 const float* __restrict__ pW3, const float* __restrict__ pb3,
                 const float* __restrict__ mask, float* __restrict__ xi)
{
    const int t = threadIdx.x;
    if (blockIdx.x >= 1024) {                 // mv3: 15 blocks x 2 j
        const int bid = blockIdx.x - 1024;
        const int j = bid * 2 + (t >> 7);
        const int lane = t & 127;
        float acc = 0.f;
        for (int k = lane; k < 1024; k += 128) {
            float h = fmaxf(pvec[k] + pb2[k], 0.f);
            acc = fmaf(h, pW3[k * 30 + j], acc);
        }
        #pragma unroll
        for (int off = 32; off > 0; off >>= 1) acc += __shfl_down(acc, off, 64);
        __shared__ float red[4];
        if ((t & 63) == 0) red[t >> 6] = acc;
        __syncthreads();
        if ((t & 127) == 0)
            xi[j] = (red[t >> 6] + red[(t >> 6) + 1] + pb3[j]) * mask[j];
        return;
    }
    const int i4 = blockIdx.x * 256 + t;
    float4 s = ((const float4*)P)[i4];
    #pragma unroll
    for (int p = 1; p < 8; ++p) {
        float4 q = ((const float4*)(P + (long)p * 1048576))[i4];
        s.x += q.x; s.y += q.y; s.z += q.z; s.w += q.w;
    }
    const int c0 = (i4 << 2) & 1023;
    float4 bv = *(const float4*)&bias[c0];
    float4 v;
    v.x = fmaxf(s.x + bv.x, 0.f);
    v.y = fmaxf(s.y + bv.y, 0.f);
    v.z = fmaxf(s.z + bv.z, 0.f);
    v.w = fmaxf(s.w + bv.w, 0.f);
    ((float4*)H2)[i4] = v;
}

// ---------------- pad nW3 (1024x150) -> B3p (1024x192, zero-padded) -----------
__global__ __launch_bounds__(256)
void pad_w3(const float* __restrict__ w, float* __restrict__ o)
{
    const int i = blockIdx.x * 256 + threadIdx.x;   // 196608
    const int k = i / 192, c = i - k * 192;
    o[i] = (c < 150) ? w[k * 150 + c] : 0.f;
}

// ---------------- ode: GEMM3 16-way reduce + basis/rhs/trapezoid, 4 b/block ---
__global__ __launch_bounds__(256)
void ode_kernel(const float* __restrict__ P3, const float* __restrict__ nb3,
                const float* __restrict__ xi, float* __restrict__ varp,
                float* __restrict__ out0, float* __restrict__ steps,
                float* __restrict__ eps)
{
    const int t  = threadIdx.x;
    const int bl = t >> 6;                    // 0..3
    const int b  = blockIdx.x * 4 + bl;
    const int lt = t & 63;
    __shared__ float s_var[4][152];
    __shared__ float s_xi[30];
    __shared__ float s_rhs[4][50][3];
    if (t < 30) s_xi[t] = xi[t];
    for (int i = lt; i < 150; i += 64) {
        float v = nb3[i];
        #pragma unroll
        for (int s = 0; s < 16; ++s) v += P3[s * 196608 + b * 192 + i];
        s_var[bl][i] = v;
        varp[b * 150 + i] = v;
    }
    __syncthreads();
    if (lt < 50) {
        const float v0 = s_var[bl][lt * 3 + 0];
        const float v1 = s_var[bl][lt * 3 + 1];
        const float v2 = s_var[bl][lt * 3 + 2];
        const float bas[10] = {1.f, v0, v1, v2,
                               v0 * v0, v0 * v1, v0 * v2,
                               v1 * v1, v1 * v2, v2 * v2};
        #pragma unroll
        for (int d = 0; d < 3; ++d) {
            float r = 0.f;
            #pragma unroll
            for (int k = 0; k < 10; ++k) r = fmaf(bas[k], s_xi[k * 3 + d], r);
            s_rhs[bl][lt][d] = r;
        }
    }
    __syncthreads();
    if (lt < 3) {
        float x = s_var[bl][lt];              // iv = var[b,0,lt]
        out0[b * 150 + lt] = x;
        for (int n = 1; n < 50; ++n) {
            x = fmaf(0.005f, s_rhs[bl][n - 1][lt] + s_rhs[bl][n][lt], x);
            out0[b * 150 + n * 3 + lt] = x;
        }
        eps[b * 3 + lt] = 0.f;
    }
    for (int i = lt; i < 147; i += 64) steps[b * 147 + i] = 0.01f;
}

extern "C" void kernel_launch(void* const* d_in, const int* in_sizes, int n_in,
                              void* d_out, int out_size, void* d_ws, size_t ws_size,
                              hipStream_t stream)
{
    const float* net_iv   = (const float*)d_in[0];
    const float* param_in = (const float*)d_in[1];
    const float* pW1 = (const float*)d_in[2];
    const float* pb1 = (const float*)d_in[3];
    const float* pW2 = (const float*)d_in[4];
    const float* pb2 = (const float*)d_in[5];
    const float* pW3 = (const float*)d_in[6];
    const float* pb3 = (const float*)d_in[7];
    const float* nW1 = (const float*)d_in[8];
    const float* nb1 = (const float*)d_in[9];
    const float* nW2 = (const float*)d_in[10];
    const float* nb2 = (const float*)d_in[11];
    const float* nW3 = (const float*)d_in[12];
    const float* nb3 = (const float*)d_in[13];
    const float* mask= (const float*)d_in[14];

    float* out = (float*)d_out;
    float* out0p  = out + OUT0_OFF;
    float* stepsp = out + STEPS_OFF;
    float* epsp   = out + EPS_OFF;
    float* varp   = out + VAR_OFF;
    float* xip    = out + XI_OFF;

    // ws layout (floats); ws = 256 MiB, we use ~54 MB.
    float* H1   = (float*)d_ws;              // 1048576
    float* P2   = H1 + 1048576;              // 8 x 1048576 (GEMM2 partials)
    float* H2   = P2 + 8388608;              // 1048576
    float* P3   = H2 + 1048576;              // 16 x 196608 (GEMM3 partials)
    float* B3p  = P3 + 3145728;              // 196608 (padded nW3)
    float* pvec = B3p + 196608;              // 1024
    float* h1p  = pvec + 1024;               // 1024

    // pad nW3 -> B3p (independent, run first)
    hipLaunchKernelGGL(pad_w3, dim3(768), dim3(256), 0, stream, nW3, B3p);

    // k1: GEMM1 (+ mv1 piggyback on bx==16)
    hipLaunchKernelGGL(gemm1_k150, dim3(17, 32), dim3(128), 0, stream,
                       net_iv, nW1, nb1, H1, param_in, pW1, pb1, h1p);

    // k2: GEMM2 64x64, 4x4 micro, split-K=8 -> 2048 blocks (+ mv2 on z==8)
    hipLaunchKernelGGL((gemm44<true>), dim3(16, 16, 9), dim3(256), 0, stream,
                       H1, nW2, P2, 1024, 1024, 128, 1048576L, 8,
                       h1p, pW2, pvec);

    // k3: reduce 8 partials + bias + relu -> H2 (+ mv3 piggyback)
    hipLaunchKernelGGL(reduce8_mv3, dim3(1039), dim3(256), 0, stream,
                       P2, nb2, H2, pvec, pb2, pW3, pb3, mask, xip);

    // k4: GEMM3 64x64, 4x4 micro, split-K=16 -> 768 blocks, padded B (N=192)
    hipLaunchKernelGGL((gemm44<false>), dim3(3, 16, 16), dim3(256), 0, stream,
                       H2, B3p, P3, 1024, 192, 64, 196608L, 16,
                       nullptr, nullptr, nullptr);

    // k5: ode (reduce 16 partials + basis/rhs/trapezoid + fills)
    hipLaunchKernelGGL(ode_kernel, dim3(256), dim3(256), 0, stream,
                       P3, nb3, xip, varp, out0p, stepsp, epsp);
}

// Round 8
// 84.889 us; speedup vs baseline: 2.4041x; 1.1730x over previous
//
#include <hip/hip_runtime.h>

// Output layout (flat f32, reference return order):
//   out0 : (1024,50,3)  @ 0       (153600)
//   steps: (1024,3,49)  @ 153600  (150528)  all 0.01
//   eps  : (1024,3)     @ 304128  (3072)    analytic 0
//   var  : (1024,50,3)  @ 307200  (153600)
//   xi   : (1,10,3)     @ 460800  (30)
#define OUT0_OFF  0
#define STEPS_OFF 153600
#define EPS_OFF   304128
#define VAR_OFF   307200
#define XI_OFF    460800

__device__ __forceinline__ void fma16v(const float4& av, const float4& bv,
                                       float acc[4][4]) {
    const float a_[4] = {av.x, av.y, av.z, av.w};
    const float b_[4] = {bv.x, bv.y, bv.z, bv.w};
    #pragma unroll
    for (int i = 0; i < 4; ++i)
        #pragma unroll
        for (int j = 0; j < 4; ++j)
            acc[i][j] = fmaf(a_[i], b_[j], acc[i][j]);
}

// ---------------- GEMM1 + mv1 piggyback ---------------------------------------
__global__ __launch_bounds__(128)
void gemm1_k150(const float* __restrict__ A, const float* __restrict__ B,
                const float* __restrict__ bias, float* __restrict__ C,
                const float* __restrict__ px, const float* __restrict__ pW1,
                const float* __restrict__ pb1, float* __restrict__ h1p)
{
    __shared__ __align__(16) float As[150][36];   // transposed A, 21.6 KB
    __shared__ __align__(16) float Bs[150][64];   // 38.4 KB
    const int t = threadIdx.x;

    if (blockIdx.x == 16) {                       // mv1: 32 blocks x 32 j
        float* red = &As[0][0];
        const int jj = t & 31, kg = t >> 5;       // 4 kgroups x 16 k
        const int j = blockIdx.y * 32 + jj;
        float acc = 0.f;
        for (int k = kg * 16; k < kg * 16 + 16; ++k)
            acc = fmaf(px[k], pW1[k * 1024 + j], acc);
        red[kg * 32 + jj] = acc;
        __syncthreads();
        if (kg == 0) {
            float s = red[jj] + red[32 + jj] + red[64 + jj] + red[96 + jj];
            h1p[j] = fmaxf(s + pb1[j], 0.f);
        }
        return;
    }

    const int col0 = blockIdx.x * 64;
    const int row0 = blockIdx.y * 32;

    for (int i = t; i < 4800; i += 128) {
        const int r = i / 150;
        const int k = i - r * 150;
        As[k][r] = A[row0 * 150 + i];
    }
    {
        const int c4 = (t & 15) * 4;
        for (int k = t >> 4; k < 150; k += 8)
            *(float4*)&Bs[k][c4] = *(const float4*)(B + k * 1024 + col0 + c4);
    }
    __syncthreads();

    const int tx4 = (t & 15) * 4;
    const int ty4 = (t >> 4) * 4;     // 0..28
    float acc[4][4] = {};
    float4 aA = *(const float4*)&As[0][ty4], bA = *(const float4*)&Bs[0][tx4];
    float4 aB = *(const float4*)&As[1][ty4], bB = *(const float4*)&Bs[1][tx4];
    #pragma unroll 5
    for (int k = 0; k < 150; k += 2) {
        float4 aN0 = {}, bN0 = {}, aN1 = {}, bN1 = {};
        if (k + 2 < 150) {
            aN0 = *(const float4*)&As[k + 2][ty4];
            bN0 = *(const float4*)&Bs[k + 2][tx4];
        }
        if (k + 3 < 150) {
            aN1 = *(const float4*)&As[k + 3][ty4];
            bN1 = *(const float4*)&Bs[k + 3][tx4];
        }
        fma16v(aA, bA, acc);
        fma16v(aB, bB, acc);
        aA = aN0; bA = bN0; aB = aN1; bB = bN1;
    }
    #pragma unroll
    for (int i = 0; i < 4; ++i) {
        const int r = row0 + ty4 + i;
        #pragma unroll
        for (int j = 0; j < 4; ++j) {
            const int c = col0 + tx4 + j;
            C[r * 1024 + c] = fmaxf(acc[i][j] + bias[c], 0.f);
        }
    }
}

// ---------------- gemm44: 64x64 tile, 4x4 micro, 256 thr, BK=16 dbuf ----------
// R3-proven at kchunk=512/SK=2 (40.3 us): LDS-read-issue-bound — do NOT
// shorten kchunk (R7: SK=8/nk=8 -> 60 us from prologue/drain bubbles).
template<bool MV2>
__global__ __launch_bounds__(256, 1)
void gemm44(const float* __restrict__ A, const float* __restrict__ B,
            float* __restrict__ C, int lda, int N, int kchunk, long pstride,
            int SK, const float* __restrict__ mx, const float* __restrict__ mW,
            float* __restrict__ my)
{
    __shared__ __align__(16) float As[2][16][68];
    __shared__ __align__(16) float Bs[2][16][64];
    const int t = threadIdx.x;

    if constexpr (MV2) {
        if (blockIdx.z == (unsigned)SK) {
            const int idx = blockIdx.y * gridDim.x + blockIdx.x;
            if (idx >= 64) return;            // only 64 blocks needed
            float* red = &As[0][0][0];
            const int jj = t & 15, kg = t >> 4;
            const int j = idx * 16 + jj;
            float acc = 0.f;
            const int k0 = kg * 64;
            for (int k = k0; k < k0 + 64; ++k)
                acc = fmaf(mx[k], mW[k * 1024 + j], acc);
            red[kg * 16 + jj] = acc;
            __syncthreads();
            if (kg == 0) {
                float s = 0.f;
                #pragma unroll
                for (int g = 0; g < 16; ++g) s += red[g * 16 + jj];
                my[j] = s;
            }
            return;
        }
    }

    const int col0 = blockIdx.x * 64;
    const int row0 = blockIdx.y * 64;
    const int k0   = blockIdx.z * kchunk;
    const int nk   = kchunk >> 4;

    const int ar = t >> 2, ak = (t & 3) << 2;     // A stage: row, k-quad
    const int bk = t >> 4, bc = (t & 15) << 2;    // B stage: k, col-quad
    const float* Ap = A + (long)(row0 + ar) * lda + k0 + ak;
    const float* Bp0 = B + (long)(k0 + bk) * N + col0 + bc;

    float4 ga, gb;
    auto loadG = [&](int kt) {
        ga = *(const float4*)(Ap + kt * 16);
        gb = *(const float4*)(Bp0 + (long)kt * 16 * N);
    };
    auto writeL = [&](int buf) {
        As[buf][ak + 0][ar] = ga.x;
        As[buf][ak + 1][ar] = ga.y;
        As[buf][ak + 2][ar] = ga.z;
        As[buf][ak + 3][ar] = ga.w;
        *(float4*)&Bs[buf][bk][bc] = gb;
    };

    loadG(0);
    writeL(0);
    __syncthreads();

    const int tx4 = (t & 15) << 2;
    const int ty4 = (t >> 4) << 2;
    float acc[4][4] = {};
    for (int kt = 0; kt < nk; ++kt) {
        const int cur = kt & 1;
        if (kt + 1 < nk) loadG(kt + 1);          // T14: issue early

        float4 aA = *(const float4*)&As[cur][0][ty4];
        float4 bA = *(const float4*)&Bs[cur][0][tx4];
        float4 aB = *(const float4*)&As[cur][1][ty4];
        float4 bB = *(const float4*)&Bs[cur][1][tx4];
        #pragma unroll
        for (int kk = 0; kk < 16; kk += 2) {
            float4 aN0 = {}, bN0 = {}, aN1 = {}, bN1 = {};
            if (kk + 2 < 16) {
                aN0 = *(const float4*)&As[cur][kk + 2][ty4];
                bN0 = *(const float4*)&Bs[cur][kk + 2][tx4];
            }
            if (kk + 3 < 16) {
                aN1 = *(const float4*)&As[cur][kk + 3][ty4];
                bN1 = *(const float4*)&Bs[cur][kk + 3][tx4];
            }
            fma16v(aA, bA, acc);
            fma16v(aB, bB, acc);
            aA = aN0; bA = bN0; aB = aN1; bB = bN1;
        }

        if (kt + 1 < nk) writeL(cur ^ 1);        // write late
        __syncthreads();
    }

    float* Cb = C + (long)blockIdx.z * pstride;
    #pragma unroll
    for (int i = 0; i < 4; ++i) {
        const long r = row0 + ty4 + i;
        float4 v = {acc[i][0], acc[i][1], acc[i][2], acc[i][3]};
        *(float4*)&Cb[r * N + col0 + tx4] = v;
    }
}

// ---------------- gemm32: 32x64 tile, 4x4 micro, 128 thr, BK=16 dbuf ----------
// For GEMM3 (M=1024, N=192 padded, K=1024): grid (3,32,SK) -> 96*SK blocks,
// unguarded vector loads (B padded), same rotation as gemm44.
__global__ __launch_bounds__(128, 1)
void gemm32(const float* __restrict__ A, const float* __restrict__ B,
            float* __restrict__ C, int lda, int N, int kchunk, long pstride)
{
    __shared__ __align__(16) float As[2][16][36];
    __shared__ __align__(16) float Bs[2][16][64];
    const int t = threadIdx.x;
    const int col0 = blockIdx.x * 64;
    const int row0 = blockIdx.y * 32;
    const int k0   = blockIdx.z * kchunk;
    const int nk   = kchunk >> 4;

    const int ar = t >> 2, ak = (t & 3) << 2;     // 32 rows x 1 float4
    const int bk = t >> 4, bc = (t & 15) << 2;    // 8 k-rows x 16 col-quads (x2)
    const float* Ap  = A + (long)(row0 + ar) * lda + k0 + ak;
    const float* Bp0 = B + (long)(k0 + bk) * N + col0 + bc;

    float4 ga, gb0, gb1;
    auto loadG = [&](int kt) {
        ga  = *(const float4*)(Ap + kt * 16);
        gb0 = *(const float4*)(Bp0 + (long)kt * 16 * N);
        gb1 = *(const float4*)(Bp0 + ((long)kt * 16 + 8) * N);
    };
    auto writeL = [&](int buf) {
        As[buf][ak + 0][ar] = ga.x;
        As[buf][ak + 1][ar] = ga.y;
        As[buf][ak + 2][ar] = ga.z;
        As[buf][ak + 3][ar] = ga.w;
        *(float4*)&Bs[buf][bk][bc]     = gb0;
        *(float4*)&Bs[buf][bk + 8][bc] = gb1;
    };

    loadG(0);
    writeL(0);
    __syncthreads();

    const int tx4 = (t & 15) << 2;
    const int ty4 = (t >> 4) << 2;                // 0..28
    float acc[4][4] = {};
    for (int kt = 0; kt < nk; ++kt) {
        const int cur = kt & 1;
        if (kt + 1 < nk) loadG(kt + 1);

        float4 aA = *(const float4*)&As[cur][0][ty4];
        float4 bA = *(const float4*)&Bs[cur][0][tx4];
        float4 aB = *(const float4*)&As[cur][1][ty4];
        float4 bB = *(const float4*)&Bs[cur][1][tx4];
        #pragma unroll
        for (int kk = 0; kk < 16; kk += 2) {
            float4 aN0 = {}, bN0 = {}, aN1 = {}, bN1 = {};
            if (kk + 2 < 16) {
                aN0 = *(const float4*)&As[cur][kk + 2][ty4];
                bN0 = *(const float4*)&Bs[cur][kk + 2][tx4];
            }
            if (kk + 3 < 16) {
                aN1 = *(const float4*)&As[cur][kk + 3][ty4];
                bN1 = *(const float4*)&Bs[cur][kk + 3][tx4];
            }
            fma16v(aA, bA, acc);
            fma16v(aB, bB, acc);
            aA = aN0; bA = bN0; aB = aN1; bB = bN1;
        }

        if (kt + 1 < nk) writeL(cur ^ 1);
        __syncthreads();
    }

    float* Cb = C + (long)blockIdx.z * pstride;
    #pragma unroll
    for (int i = 0; i < 4; ++i) {
        const long r = row0 + ty4 + i;
        float4 v = {acc[i][0], acc[i][1], acc[i][2], acc[i][3]};
        *(float4*)&Cb[r * N + col0 + tx4] = v;
    }
}

// ---------------- reduce GEMM2 split-K=2 (+bias+relu) + mv3 piggyback ---------
__global__ __launch_bounds__(256)
void reduce2_mv3(const float* __restrict__ P, const float* __restrict__ bias,
                 float* __restrict__ H2,
                 const float* __restrict__ pvec, const float* __restrict__ pb2,
                 const float* __restrict__ pW3, const float* __restrict__ pb3,
                 const float* __restrict__ mask, float* __restrict__ xi)
{
    const int t = threadIdx.x;
    if (blockIdx.x >= 1024) {                 // mv3: 15 blocks x 2 j
        const int bid = blockIdx.x - 1024;
        const int j = bid * 2 + (t >> 7);
        const int lane = t & 127;
        float acc = 0.f;
        for (int k = lane; k < 1024; k += 128) {
            float h = fmaxf(pvec[k] + pb2[k], 0.f);
            acc = fmaf(h, pW3[k * 30 + j], acc);
        }
        #pragma unroll
        for (int off = 32; off > 0; off >>= 1) acc += __shfl_down(acc, off, 64);
        __shared__ float red[4];
        if ((t & 63) == 0) red[t >> 6] = acc;
        __syncthreads();
        if ((t & 127) == 0)
            xi[j] = (red[t >> 6] + red[(t >> 6) + 1] + pb3[j]) * mask[j];
        return;
    }
    const int i4 = blockIdx.x * 256 + t;
    float4 p = ((const float4*)P)[i4];
    float4 q = ((const float4*)(P + 1048576))[i4];
    const int c0 = (i4 << 2) & 1023;
    float4 bv = *(const float4*)&bias[c0];
    float4 v;
    v.x = fmaxf(p.x + q.x + bv.x, 0.f);
    v.y = fmaxf(p.y + q.y + bv.y, 0.f);
    v.z = fmaxf(p.z + q.z + bv.z, 0.f);
    v.w = fmaxf(p.w + q.w + bv.w, 0.f);
    ((float4*)H2)[i4] = v;
}

// ---------------- pad nW3 (1024x150) -> B3p (1024x192, zero-padded) -----------
__global__ __launch_bounds__(256)
void pad_w3(const float* __restrict__ w, float* __restrict__ o)
{
    const int i = blockIdx.x * 256 + threadIdx.x;   // 196608
    const int k = i / 192, c = i - k * 192;
    o[i] = (c < 150) ? w[k * 150 + c] : 0.f;
}

// ---------------- ode: GEMM3 8-way reduce + basis/rhs/trapezoid, 4 b/block ----
__global__ __launch_bounds__(256)
void ode_kernel(const float* __restrict__ P3, const float* __restrict__ nb3,
                const float* __restrict__ xi, float* __restrict__ varp,
                float* __restrict__ out0, float* __restrict__ steps,
                float* __restrict__ eps)
{
    const int t  = threadIdx.x;
    const int bl = t >> 6;                    // 0..3
    const int b  = blockIdx.x * 4 + bl;
    const int lt = t & 63;
    __shared__ float s_var[4][152];
    __shared__ float s_xi[30];
    __shared__ float s_rhs[4][50][3];
    if (t < 30) s_xi[t] = xi[t];
    for (int i = lt; i < 150; i += 64) {
        float v = nb3[i];
        #pragma unroll
        for (int s = 0; s < 8; ++s) v += P3[s * 196608 + b * 192 + i];
        s_var[bl][i] = v;
        varp[b * 150 + i] = v;
    }
    __syncthreads();
    if (lt < 50) {
        const float v0 = s_var[bl][lt * 3 + 0];
        const float v1 = s_var[bl][lt * 3 + 1];
        const float v2 = s_var[bl][lt * 3 + 2];
        const float bas[10] = {1.f, v0, v1, v2,
                               v0 * v0, v0 * v1, v0 * v2,
                               v1 * v1, v1 * v2, v2 * v2};
        #pragma unroll
        for (int d = 0; d < 3; ++d) {
            float r = 0.f;
            #pragma unroll
            for (int k = 0; k < 10; ++k) r = fmaf(bas[k], s_xi[k * 3 + d], r);
            s_rhs[bl][lt][d] = r;
        }
    }
    __syncthreads();
    if (lt < 3) {
        float x = s_var[bl][lt];              // iv = var[b,0,lt]
        out0[b * 150 + lt] = x;
        for (int n = 1; n < 50; ++n) {
            x = fmaf(0.005f, s_rhs[bl][n - 1][lt] + s_rhs[bl][n][lt], x);
            out0[b * 150 + n * 3 + lt] = x;
        }
        eps[b * 3 + lt] = 0.f;
    }
    for (int i = lt; i < 147; i += 64) steps[b * 147 + i] = 0.01f;
}

extern "C" void kernel_launch(void* const* d_in, const int* in_sizes, int n_in,
                              void* d_out, int out_size, void* d_ws, size_t ws_size,
                              hipStream_t stream)
{
    const float* net_iv   = (const float*)d_in[0];
    const float* param_in = (const float*)d_in[1];
    const float* pW1 = (const float*)d_in[2];
    const float* pb1 = (const float*)d_in[3];
    const float* pW2 = (const float*)d_in[4];
    const float* pb2 = (const float*)d_in[5];
    const float* pW3 = (const float*)d_in[6];
    const float* pb3 = (const float*)d_in[7];
    const float* nW1 = (const float*)d_in[8];
    const float* nb1 = (const float*)d_in[9];
    const float* nW2 = (const float*)d_in[10];
    const float* nb2 = (const float*)d_in[11];
    const float* nW3 = (const float*)d_in[12];
    const float* nb3 = (const float*)d_in[13];
    const float* mask= (const float*)d_in[14];

    float* out = (float*)d_out;
    float* out0p  = out + OUT0_OFF;
    float* stepsp = out + STEPS_OFF;
    float* epsp   = out + EPS_OFF;
    float* varp   = out + VAR_OFF;
    float* xip    = out + XI_OFF;

    // ws layout (floats); ~24 MB of the 256 MiB ws.
    float* H1   = (float*)d_ws;              // 1048576
    float* P2   = H1 + 1048576;              // 2 x 1048576 (GEMM2 partials)
    float* H2   = P2 + 2097152;              // 1048576
    float* P3   = H2 + 1048576;              // 8 x 196608 (GEMM3 partials)
    float* B3p  = P3 + 1572864;              // 196608 (padded nW3)
    float* pvec = B3p + 196608;              // 1024
    float* h1p  = pvec + 1024;               // 1024

    // pad nW3 -> B3p (independent, run first)
    hipLaunchKernelGGL(pad_w3, dim3(768), dim3(256), 0, stream, nW3, B3p);

    // k1: GEMM1 (+ mv1 piggyback on bx==16)
    hipLaunchKernelGGL(gemm1_k150, dim3(17, 32), dim3(128), 0, stream,
                       net_iv, nW1, nb1, H1, param_in, pW1, pb1, h1p);

    // k2: GEMM2 64x64, 4x4 micro, kchunk=512, split-K=2 (+ mv2 on z==2)
    hipLaunchKernelGGL((gemm44<true>), dim3(16, 16, 3), dim3(256), 0, stream,
                       H1, nW2, P2, 1024, 1024, 512, 1048576L, 2,
                       h1p, pW2, pvec);

    // k3: reduce 2 partials + bias + relu -> H2 (+ mv3 piggyback)
    hipLaunchKernelGGL(reduce2_mv3, dim3(1039), dim3(256), 0, stream,
                       P2, nb2, H2, pvec, pb2, pW3, pb3, mask, xip);

    // k4: GEMM3 32x64 tile, split-K=8 -> 768 blocks, nk=8, padded B (N=192)
    hipLaunchKernelGGL(gemm32, dim3(3, 32, 8), dim3(128), 0, stream,
                       H2, B3p, P3, 1024, 192, 128, 196608L);

    // k5: ode (reduce 8 partials + basis/rhs/trapezoid + fills)
    hipLaunchKernelGGL(ode_kernel, dim3(256), dim3(256), 0, stream,
                       P3, nb3, xip, varp, out0p, stepsp, epsp);
}